// Round 1
// baseline (2469.263 us; speedup 1.0000x reference)
//
#include <hip/hip_runtime.h>
#include <hip/hip_bf16.h>

// Problem constants
#define N_ROWS 16384   // 8*2048
#define DDIM   512
#define KCODES 8192
#define BETA   0.25f
#define DECAY  0.99f
#define ONE_MINUS_DECAY 0.01f
#define EMA_EPS 1e-5f

// Output layout (floats, concatenated in reference return order)
#define O_Z    0                 // z_out: 8388608
#define O_LOSS 8388608           // vq_loss: 1
#define O_CS   8388609           // new_ema_cluster_size: 8192
#define O_AVG  8396801           // new_ema_embed_avg: 4194304
#define O_CB   12591105          // new_codebook: 4194304

// Workspace layout (bytes)
#define WS_KEYS 0                          // u64[16384] = 131072 B
#define WS_CNT  131072                     // float[8192] raw batch counts
#define WS_ESQ  (131072 + 32768)           // float[8192] e_sq

// ---------------- Kernel A: e_sq[k] = sum(e[k]^2) ----------------
__global__ void esq_kernel(const float* __restrict__ cb, float* __restrict__ e_sq) {
    int k = blockIdx.x;
    int t = threadIdx.x; // 64 threads = 1 wave
    const float4* r = (const float4*)(cb + (size_t)k * DDIM);
    float4 a = r[t];
    float4 b = r[t + 64];
    float s = a.x*a.x + a.y*a.y + a.z*a.z + a.w*a.w
            + b.x*b.x + b.y*b.y + b.z*b.z + b.w*b.w;
    #pragma unroll
    for (int o = 32; o > 0; o >>= 1) s += __shfl_down(s, o);
    if (t == 0) e_sq[k] = s;
}

// ---------------- Kernel P: init EMA outputs + zero loss ----------------
__global__ void prepass_kernel(const float* __restrict__ ema_cs,
                               const float* __restrict__ ema_avg,
                               float* __restrict__ out) {
    int i = blockIdx.x * 256 + threadIdx.x;
    if (i < KCODES * DDIM) out[O_AVG + i] = DECAY * ema_avg[i];
    if (i < KCODES)        out[O_CS + i]  = DECAY * ema_cs[i];
    if (i == 0)            out[O_LOSS]    = 0.0f;
}

// ---------------- Kernel B: fp32 distance GEMM + argmin ----------------
// dist(n,k) = e_sq[k] - 2 * dot(z_n, e_k)   (z_sq is row-constant, irrelevant to argmin)
#define BM 64
#define BN 128
#define BK 32
__global__ __launch_bounds__(256) void dist_argmin_kernel(
    const float* __restrict__ z, const float* __restrict__ cb,
    const float* __restrict__ e_sq, unsigned long long* __restrict__ keys) {
    __shared__ float zt[BK][BM + 4];   // transposed: zt[d][row]
    __shared__ float et[BK][BN + 4];   // transposed: et[d][code]

    const int tid = threadIdx.x;
    const int cbk = blockIdx.x;  // code tile: 64 tiles of 128
    const int rbk = blockIdx.y;  // row tile: 256 tiles of 64

    float acc[4][8];
    #pragma unroll
    for (int i = 0; i < 4; i++)
        #pragma unroll
        for (int j = 0; j < 8; j++) acc[i][j] = 0.0f;

    const int tr = tid & 15;   // row group: 16 x 4 rows
    const int tc = tid >> 4;   // code group: 16 x 8 codes

    for (int kc = 0; kc < DDIM; kc += BK) {
        // load z tile: 64 rows x 32 d = 512 float4
        #pragma unroll
        for (int l = 0; l < 2; l++) {
            int i = tid + l * 256;
            int row = i >> 3, dq = (i & 7) << 2;
            const float4 v = *(const float4*)&z[(size_t)(rbk * BM + row) * DDIM + kc + dq];
            zt[dq + 0][row] = v.x; zt[dq + 1][row] = v.y;
            zt[dq + 2][row] = v.z; zt[dq + 3][row] = v.w;
        }
        // load e tile: 128 codes x 32 d = 1024 float4
        #pragma unroll
        for (int l = 0; l < 4; l++) {
            int i = tid + l * 256;
            int code = i >> 3, dq = (i & 7) << 2;
            const float4 v = *(const float4*)&cb[(size_t)(cbk * BN + code) * DDIM + kc + dq];
            et[dq + 0][code] = v.x; et[dq + 1][code] = v.y;
            et[dq + 2][code] = v.z; et[dq + 3][code] = v.w;
        }
        __syncthreads();
        #pragma unroll
        for (int d = 0; d < BK; d++) {
            const float4 a  = *(const float4*)&zt[d][tr * 4];
            const float4 b0 = *(const float4*)&et[d][tc * 8];
            const float4 b1 = *(const float4*)&et[d][tc * 8 + 4];
            const float av[4] = {a.x, a.y, a.z, a.w};
            const float bv[8] = {b0.x, b0.y, b0.z, b0.w, b1.x, b1.y, b1.z, b1.w};
            #pragma unroll
            for (int i = 0; i < 4; i++)
                #pragma unroll
                for (int j = 0; j < 8; j++)
                    acc[i][j] = fmaf(av[i], bv[j], acc[i][j]);
        }
        __syncthreads();
    }

    // Epilogue: per-thread argmin over its 8 codes, per row.
    // Pack key = (monotone(dist) << 32) | code  -> u64 min == (min dist, then min idx)
    unsigned long long* part = (unsigned long long*)&et[0][0]; // 64 rows x 16 tc = 8 KB
    #pragma unroll
    for (int i = 0; i < 4; i++) {
        float bd = 3.4e38f;
        int bc = 0;
        #pragma unroll
        for (int j = 0; j < 8; j++) {
            int code = cbk * BN + tc * 8 + j;
            float dd = e_sq[code] - 2.0f * acc[i][j];
            if (dd < bd) { bd = dd; bc = code; }  // ascending j => first-min => lowest idx
        }
        unsigned int ub = __float_as_uint(bd);
        ub ^= (ub & 0x80000000u) ? 0xFFFFFFFFu : 0x80000000u; // order-preserving for floats
        part[(tr * 4 + i) * 16 + tc] = (((unsigned long long)ub) << 32) | (unsigned int)bc;
    }
    __syncthreads();
    if (tid < BM) {
        unsigned long long best = part[tid * 16];
        #pragma unroll
        for (int t = 1; t < 16; t++) {
            unsigned long long v = part[tid * 16 + t];
            best = (v < best) ? v : best;
        }
        atomicMin(&keys[rbk * BM + tid], best);
    }
}

// ---------------- Kernel C: gather z_q, loss, EMA scatter ----------------
__global__ __launch_bounds__(128) void gather_stats_kernel(
    const float* __restrict__ z, const float* __restrict__ cb,
    const unsigned long long* __restrict__ keys,
    float* __restrict__ out, float* __restrict__ cnt) {
    const int row = blockIdx.x;
    const int tid = threadIdx.x; // 128 threads, 4 floats each
    const int idx = (int)(unsigned int)(keys[row] & 0xFFFFFFFFull);

    const float4 zv = ((const float4*)(z  + (size_t)row * DDIM))[tid];
    const float4 ev = ((const float4*)(cb + (size_t)idx * DDIM))[tid];
    ((float4*)(out + O_Z + (size_t)row * DDIM))[tid] = ev;  // z_out == z_q (forward STE value)

    float dx = zv.x - ev.x, dy = zv.y - ev.y, dz = zv.z - ev.z, dw = zv.w - ev.w;
    float s = dx*dx + dy*dy + dz*dz + dw*dw;

    // EMA embed-avg scatter: out[O_AVG + idx*D + d] += 0.01 * z
    float* o3 = out + O_AVG + (size_t)idx * DDIM + tid * 4;
    atomicAdd(o3 + 0, ONE_MINUS_DECAY * zv.x);
    atomicAdd(o3 + 1, ONE_MINUS_DECAY * zv.y);
    atomicAdd(o3 + 2, ONE_MINUS_DECAY * zv.z);
    atomicAdd(o3 + 3, ONE_MINUS_DECAY * zv.w);

    // loss reduction (2 waves)
    #pragma unroll
    for (int o = 32; o > 0; o >>= 1) s += __shfl_down(s, o);
    __shared__ float red[2];
    if ((tid & 63) == 0) red[tid >> 6] = s;
    __syncthreads();
    if (tid == 0) {
        atomicAdd(out + O_LOSS, (red[0] + red[1]) * (BETA / (float)DDIM));
        atomicAdd(&cnt[idx], 1.0f);
        atomicAdd(out + O_CS + idx, ONE_MINUS_DECAY);
    }
}

// ---------------- Kernel D: finalize codebook ----------------
__global__ void finalize_kernel(const float* __restrict__ cb,
                                const float* __restrict__ cnt,
                                float* __restrict__ out) {
    int i = blockIdx.x * 256 + threadIdx.x;
    if (i >= KCODES * DDIM) return;
    int k = i >> 9;
    float avg = out[O_AVG + i];
    float ncs = out[O_CS + k];
    float upd = avg / (ncs + EMA_EPS);
    out[O_CB + i] = (cnt[k] > 0.0f) ? upd : cb[i];
}

extern "C" void kernel_launch(void* const* d_in, const int* in_sizes, int n_in,
                              void* d_out, int out_size, void* d_ws, size_t ws_size,
                              hipStream_t stream) {
    const float* z       = (const float*)d_in[0];
    const float* cb      = (const float*)d_in[1];
    const float* ema_cs  = (const float*)d_in[2];
    const float* ema_avg = (const float*)d_in[3];
    float* out = (float*)d_out;

    unsigned long long* keys = (unsigned long long*)((char*)d_ws + WS_KEYS);
    float* cnt  = (float*)((char*)d_ws + WS_CNT);
    float* e_sq = (float*)((char*)d_ws + WS_ESQ);

    // init: keys = +inf (0xFF..), counts = 0
    hipMemsetAsync(keys, 0xFF, N_ROWS * sizeof(unsigned long long), stream);
    hipMemsetAsync(cnt, 0, KCODES * sizeof(float), stream);

    esq_kernel<<<KCODES, 64, 0, stream>>>(cb, e_sq);
    prepass_kernel<<<(KCODES * DDIM + 255) / 256, 256, 0, stream>>>(ema_cs, ema_avg, out);
    dist_argmin_kernel<<<dim3(KCODES / BN, N_ROWS / BM), 256, 0, stream>>>(z, cb, e_sq, keys);
    gather_stats_kernel<<<N_ROWS, 128, 0, stream>>>(z, cb, keys, out, cnt);
    finalize_kernel<<<(KCODES * DDIM + 255) / 256, 256, 0, stream>>>(cb, cnt, out);
}

// Round 2
// 2106.202 us; speedup vs baseline: 1.1724x; 1.1724x over previous
//
#include <hip/hip_runtime.h>
#include <hip/hip_bf16.h>

// Problem constants
#define N_ROWS 16384   // 8*2048
#define DDIM   512
#define KCODES 8192
#define BETA   0.25f
#define DECAY  0.99f
#define ONE_MINUS_DECAY 0.01f
#define EMA_EPS 1e-5f

// Output layout (floats, concatenated in reference return order)
#define O_Z    0                 // z_out: 8388608
#define O_LOSS 8388608           // vq_loss: 1
#define O_CS   8388609           // new_ema_cluster_size: 8192
#define O_AVG  8396801           // new_ema_embed_avg: 4194304
#define O_CB   12591105          // new_codebook: 4194304

// Workspace layout (bytes)
#define WS_CNT      0            // float[8192]
#define WS_ESQ      32768        // float[8192]
#define WS_FLAGCNT  65536        // int
#define WS_FLAGLIST 65792        // int[2048]
#define WS_KEYS     73984        // u64[16384]
#define WS_TBK      205056       // u64[16384*32] = 4 MB
#define WS_TSD      4399360      // f32[16384*32] = 2 MB
// total ~6.5 MB

#define TAU  0.35f
#define RCAP 2048

typedef _Float16 half8  __attribute__((ext_vector_type(8)));
typedef float    floatx4 __attribute__((ext_vector_type(4)));

// monotone float->u32 (ascending), and inverse
__device__ __forceinline__ unsigned enc_f(float d) {
    unsigned ub = __float_as_uint(d);
    return (ub & 0x80000000u) ? ~ub : (ub | 0x80000000u);
}
__device__ __forceinline__ float dec_key(unsigned long long k) {
    unsigned ub = (unsigned)(k >> 32);
    ub = (ub & 0x80000000u) ? (ub ^ 0x80000000u) : ~ub;
    return __uint_as_float(ub);
}

// ---------------- Kernel A: e_sq[k] = sum(e[k]^2) ----------------
__global__ void esq_kernel(const float* __restrict__ cb, float* __restrict__ e_sq) {
    int k = blockIdx.x;
    int t = threadIdx.x; // 64 threads = 1 wave
    const float4* r = (const float4*)(cb + (size_t)k * DDIM);
    float4 a = r[t];
    float4 b = r[t + 64];
    float s = a.x*a.x + a.y*a.y + a.z*a.z + a.w*a.w
            + b.x*b.x + b.y*b.y + b.z*b.z + b.w*b.w;
    #pragma unroll
    for (int o = 32; o > 0; o >>= 1) s += __shfl_down(s, o);
    if (t == 0) e_sq[k] = s;
}

// ---------------- Kernel P: init EMA outputs + zero loss ----------------
__global__ void prepass_kernel(const float* __restrict__ ema_cs,
                               const float* __restrict__ ema_avg,
                               float* __restrict__ out) {
    int i = blockIdx.x * 256 + threadIdx.x;
    if (i < KCODES * DDIM) out[O_AVG + i] = DECAY * ema_avg[i];
    if (i < KCODES)        out[O_CS + i]  = DECAY * ema_cs[i];
    if (i == 0)            out[O_LOSS]    = 0.0f;
}

// ---------------- Kernel S: f16 MFMA screening ----------------
// Block: 256 threads (4 waves), tile BM=128 rows x BN=256 codes, BK=64.
// Wave w: wm=w&1 (row half 64), wn=w>>1 (code half 128). Wave tile 64x128.
// LDS f16 tiles, XOR-swizzled 16B granules: elem (row,k) at
//   row*64 + ((k/8 ^ (row&7))*8 + k%8, conflict-free b128 frag reads.
__global__ __launch_bounds__(256, 2) void screen_kernel(
    const float* __restrict__ z, const float* __restrict__ cb,
    const float* __restrict__ e_sq,
    unsigned long long* __restrict__ tbk, float* __restrict__ tsd) {
    __shared__ _Float16 zt[128 * 64];
    __shared__ _Float16 ct[256 * 64];
    __shared__ float eb_d1[2][128];
    __shared__ int   eb_c1[2][128];
    __shared__ float eb_d2[2][128];

    const int tid = threadIdx.x;
    const int bx = blockIdx.x;   // code tile (32)
    const int by = blockIdx.y;   // row tile (128)
    const int lane = tid & 63, wid = tid >> 6;
    const int wm = wid & 1, wn = wid >> 1;
    const int lr = lane & 15, lq = lane >> 4;

    floatx4 acc[4][8];
    #pragma unroll
    for (int i = 0; i < 4; i++)
        #pragma unroll
        for (int j = 0; j < 8; j++) acc[i][j] = floatx4{0.f, 0.f, 0.f, 0.f};

    for (int kc = 0; kc < DDIM; kc += 64) {
        // stage z: 128 rows x 16 quads (float4)
        #pragma unroll
        for (int l = 0; l < 8; l++) {
            int idx = tid + 256 * l;
            int row = idx >> 4, q = idx & 15;
            const float4 v = *(const float4*)&z[(size_t)(by * 128 + row) * DDIM + kc + q * 4];
            int a = row * 64 + (((q >> 1) ^ (row & 7)) << 3) + ((q & 1) << 2);
            auto p0 = __builtin_amdgcn_cvt_pkrtz(v.x, v.y);
            auto p1 = __builtin_amdgcn_cvt_pkrtz(v.z, v.w);
            float2 w; w.x = __builtin_bit_cast(float, p0); w.y = __builtin_bit_cast(float, p1);
            *(float2*)&zt[a] = w;
        }
        // stage cb: 256 rows x 16 quads
        #pragma unroll
        for (int l = 0; l < 16; l++) {
            int idx = tid + 256 * l;
            int row = idx >> 4, q = idx & 15;
            const float4 v = *(const float4*)&cb[(size_t)(bx * 256 + row) * DDIM + kc + q * 4];
            int a = row * 64 + (((q >> 1) ^ (row & 7)) << 3) + ((q & 1) << 2);
            auto p0 = __builtin_amdgcn_cvt_pkrtz(v.x, v.y);
            auto p1 = __builtin_amdgcn_cvt_pkrtz(v.z, v.w);
            float2 w; w.x = __builtin_bit_cast(float, p0); w.y = __builtin_bit_cast(float, p1);
            *(float2*)&ct[a] = w;
        }
        __syncthreads();
        #pragma unroll
        for (int kk = 0; kk < 2; kk++) {
            half8 av[4];
            #pragma unroll
            for (int mt = 0; mt < 4; mt++) {
                int row = wm * 64 + mt * 16 + lr;
                av[mt] = *(const half8*)&zt[row * 64 + (((kk * 4 + lq) ^ (row & 7)) << 3)];
            }
            #pragma unroll
            for (int nt = 0; nt < 8; nt++) {
                int row = wn * 128 + nt * 16 + lr;
                half8 bv = *(const half8*)&ct[row * 64 + (((kk * 4 + lq) ^ (row & 7)) << 3)];
                #pragma unroll
                for (int mt = 0; mt < 4; mt++)
                    acc[mt][nt] = __builtin_amdgcn_mfma_f32_16x16x32_f16(av[mt], bv, acc[mt][nt], 0, 0, 0);
            }
        }
        __syncthreads();
    }

    // Epilogue: per-row best + second over this block's 256 codes.
    float es[8];
    #pragma unroll
    for (int nt = 0; nt < 8; nt++) es[nt] = e_sq[bx * 256 + wn * 128 + nt * 16 + lr];

    #pragma unroll
    for (int mt = 0; mt < 4; mt++) {
        #pragma unroll
        for (int r = 0; r < 4; r++) {
            float d1 = 1e30f, d2 = 1e30f; int c1 = 0x7FFFFFFF;
            #pragma unroll
            for (int nt = 0; nt < 8; nt++) {
                float d = fmaf(-2.0f, acc[mt][nt][r], es[nt]);
                int c = bx * 256 + wn * 128 + nt * 16 + lr;
                bool better = (d < d1) || (d == d1 && c < c1);
                if (better) { d2 = d1; d1 = d; c1 = c; }
                else        { d2 = fminf(d2, d); }
            }
            // reduce across the 16 lanes (lr) of this quad
            #pragma unroll
            for (int off = 1; off < 16; off <<= 1) {
                float od1 = __shfl_xor(d1, off);
                int   oc1 = __shfl_xor(c1, off);
                float od2 = __shfl_xor(d2, off);
                bool better = (od1 < d1) || (od1 == d1 && oc1 < c1);
                if (better) { d2 = fminf(d1, od2); d1 = od1; c1 = oc1; }
                else        { d2 = fminf(d2, od1); }
            }
            if (lr == 0) {
                int row = wm * 64 + mt * 16 + lq * 4 + r;
                eb_d1[wn][row] = d1; eb_c1[wn][row] = c1; eb_d2[wn][row] = d2;
            }
        }
    }
    __syncthreads();
    if (tid < 128) {
        float d1a = eb_d1[0][tid], d2a = eb_d2[0][tid]; int c1a = eb_c1[0][tid];
        float d1b = eb_d1[1][tid], d2b = eb_d2[1][tid]; int c1b = eb_c1[1][tid];
        bool bbet = (d1b < d1a) || (d1b == d1a && c1b < c1a);
        float d1 = bbet ? d1b : d1a; int c1 = bbet ? c1b : c1a;
        float d2 = bbet ? fminf(d1a, d2b) : fminf(d2a, d1b);
        unsigned long long key = ((unsigned long long)enc_f(d1) << 32) | (unsigned)c1;
        int row_g = by * 128 + tid;
        tbk[(size_t)row_g * 32 + bx] = key;
        tsd[(size_t)row_g * 32 + bx] = d2;
    }
}

// ---------------- Kernel M: merge tiles, flag near-ties ----------------
__global__ void merge_kernel(const unsigned long long* __restrict__ tbk,
                             const float* __restrict__ tsd,
                             unsigned long long* __restrict__ keys,
                             int* __restrict__ flagcnt, int* __restrict__ flaglist) {
    int row = blockIdx.x * 256 + threadIdx.x;
    const unsigned long long* t = tbk + (size_t)row * 32;
    const float* s = tsd + (size_t)row * 32;
    unsigned long long kb = t[0];
    float sec = s[0];
    for (int i = 1; i < 32; i++) {
        unsigned long long k = t[i]; float s2 = s[i];
        if (k < kb) { sec = fminf(fminf(sec, s2), dec_key(kb)); kb = k; }
        else        { sec = fminf(sec, fminf(s2, dec_key(k))); }
    }
    float best = dec_key(kb);
    if (sec - best < TAU) {
        int pos = atomicAdd(flagcnt, 1);
        if (pos < RCAP) { flaglist[pos] = row; keys[row] = ~0ULL; }
        else keys[row] = kb;   // overflow fallback: keep screened result
    } else {
        keys[row] = kb;
    }
}

// ---------------- Kernel R: exact fp32 rescore of flagged rows ----------------
__global__ __launch_bounds__(256) void rescore_kernel(
    const float* __restrict__ z, const float* __restrict__ cb,
    const float* __restrict__ e_sq, const int* __restrict__ flagcnt,
    const int* __restrict__ flaglist, unsigned long long* __restrict__ keys) {
    int n = *flagcnt; n = min(n, RCAP);
    int base = blockIdx.y * 32;
    if (base >= n) return;
    __shared__ float ech[128][65];
    __shared__ float zch[32][65];
    __shared__ int ridx[32];
    const int tid = threadIdx.x;
    const int bx = blockIdx.x;
    if (tid < 32) ridx[tid] = flaglist[min(base + tid, n - 1)];
    __syncthreads();
    const int tc = tid & 31, tg = tid >> 5;  // codes tc*4.., rows tg*4..
    float acc[4][4] = {};
    for (int kc = 0; kc < DDIM; kc += 64) {
        #pragma unroll
        for (int l = 0; l < 8; l++) {
            int idx = tid + 256 * l;
            int row = idx >> 4, q = idx & 15;
            float4 v = *(const float4*)&cb[(size_t)(bx * 128 + row) * DDIM + kc + q * 4];
            ech[row][q*4+0] = v.x; ech[row][q*4+1] = v.y; ech[row][q*4+2] = v.z; ech[row][q*4+3] = v.w;
        }
        #pragma unroll
        for (int l = 0; l < 2; l++) {
            int idx = tid + 256 * l;
            int row = idx >> 4, q = idx & 15;
            float4 v = *(const float4*)&z[(size_t)ridx[row] * DDIM + kc + q * 4];
            zch[row][q*4+0] = v.x; zch[row][q*4+1] = v.y; zch[row][q*4+2] = v.z; zch[row][q*4+3] = v.w;
        }
        __syncthreads();
        for (int k = 0; k < 64; k++) {
            float a0 = zch[tg*4+0][k], a1 = zch[tg*4+1][k], a2 = zch[tg*4+2][k], a3 = zch[tg*4+3][k];
            float b0 = ech[tc*4+0][k], b1 = ech[tc*4+1][k], b2 = ech[tc*4+2][k], b3 = ech[tc*4+3][k];
            acc[0][0] = fmaf(a0,b0,acc[0][0]); acc[0][1] = fmaf(a0,b1,acc[0][1]);
            acc[0][2] = fmaf(a0,b2,acc[0][2]); acc[0][3] = fmaf(a0,b3,acc[0][3]);
            acc[1][0] = fmaf(a1,b0,acc[1][0]); acc[1][1] = fmaf(a1,b1,acc[1][1]);
            acc[1][2] = fmaf(a1,b2,acc[1][2]); acc[1][3] = fmaf(a1,b3,acc[1][3]);
            acc[2][0] = fmaf(a2,b0,acc[2][0]); acc[2][1] = fmaf(a2,b1,acc[2][1]);
            acc[2][2] = fmaf(a2,b2,acc[2][2]); acc[2][3] = fmaf(a2,b3,acc[2][3]);
            acc[3][0] = fmaf(a3,b0,acc[3][0]); acc[3][1] = fmaf(a3,b1,acc[3][1]);
            acc[3][2] = fmaf(a3,b2,acc[3][2]); acc[3][3] = fmaf(a3,b3,acc[3][3]);
        }
        __syncthreads();
    }
    #pragma unroll
    for (int j = 0; j < 4; j++) {
        int code = bx * 128 + tc * 4 + j;
        float esv = e_sq[code];
        #pragma unroll
        for (int i = 0; i < 4; i++) {
            float d = fmaf(-2.0f, acc[i][j], esv);
            unsigned long long key = ((unsigned long long)enc_f(d) << 32) | (unsigned)code;
            atomicMin(&keys[ridx[tg * 4 + i]], key);
        }
    }
}

// ---------------- Kernel C: gather z_q, loss, EMA scatter ----------------
__global__ __launch_bounds__(128) void gather_stats_kernel(
    const float* __restrict__ z, const float* __restrict__ cb,
    const unsigned long long* __restrict__ keys,
    float* __restrict__ out, float* __restrict__ cnt) {
    const int row = blockIdx.x;
    const int tid = threadIdx.x; // 128 threads, 4 floats each
    const int idx = (int)(unsigned int)(keys[row] & 0xFFFFFFFFull);

    const float4 zv = ((const float4*)(z  + (size_t)row * DDIM))[tid];
    const float4 ev = ((const float4*)(cb + (size_t)idx * DDIM))[tid];
    ((float4*)(out + O_Z + (size_t)row * DDIM))[tid] = ev;

    float dx = zv.x - ev.x, dy = zv.y - ev.y, dz = zv.z - ev.z, dw = zv.w - ev.w;
    float s = dx*dx + dy*dy + dz*dz + dw*dw;

    float* o3 = out + O_AVG + (size_t)idx * DDIM + tid * 4;
    atomicAdd(o3 + 0, ONE_MINUS_DECAY * zv.x);
    atomicAdd(o3 + 1, ONE_MINUS_DECAY * zv.y);
    atomicAdd(o3 + 2, ONE_MINUS_DECAY * zv.z);
    atomicAdd(o3 + 3, ONE_MINUS_DECAY * zv.w);

    #pragma unroll
    for (int o = 32; o > 0; o >>= 1) s += __shfl_down(s, o);
    __shared__ float red[2];
    if ((tid & 63) == 0) red[tid >> 6] = s;
    __syncthreads();
    if (tid == 0) {
        atomicAdd(out + O_LOSS, (red[0] + red[1]) * (BETA / (float)DDIM));
        atomicAdd(&cnt[idx], 1.0f);
        atomicAdd(out + O_CS + idx, ONE_MINUS_DECAY);
    }
}

// ---------------- Kernel D: finalize codebook ----------------
__global__ void finalize_kernel(const float* __restrict__ cb,
                                const float* __restrict__ cnt,
                                float* __restrict__ out) {
    int i = blockIdx.x * 256 + threadIdx.x;
    if (i >= KCODES * DDIM) return;
    int k = i >> 9;
    float avg = out[O_AVG + i];
    float ncs = out[O_CS + k];
    float upd = avg / (ncs + EMA_EPS);
    out[O_CB + i] = (cnt[k] > 0.0f) ? upd : cb[i];
}

extern "C" void kernel_launch(void* const* d_in, const int* in_sizes, int n_in,
                              void* d_out, int out_size, void* d_ws, size_t ws_size,
                              hipStream_t stream) {
    const float* z       = (const float*)d_in[0];
    const float* cb      = (const float*)d_in[1];
    const float* ema_cs  = (const float*)d_in[2];
    const float* ema_avg = (const float*)d_in[3];
    float* out = (float*)d_out;

    float* cnt  = (float*)((char*)d_ws + WS_CNT);
    float* e_sq = (float*)((char*)d_ws + WS_ESQ);
    int* flagcnt = (int*)((char*)d_ws + WS_FLAGCNT);
    int* flaglist = (int*)((char*)d_ws + WS_FLAGLIST);
    unsigned long long* keys = (unsigned long long*)((char*)d_ws + WS_KEYS);
    unsigned long long* tbk = (unsigned long long*)((char*)d_ws + WS_TBK);
    float* tsd = (float*)((char*)d_ws + WS_TSD);

    hipMemsetAsync(cnt, 0, KCODES * sizeof(float), stream);
    hipMemsetAsync(flagcnt, 0, sizeof(int), stream);

    esq_kernel<<<KCODES, 64, 0, stream>>>(cb, e_sq);
    prepass_kernel<<<(KCODES * DDIM + 255) / 256, 256, 0, stream>>>(ema_cs, ema_avg, out);
    screen_kernel<<<dim3(KCODES / 256, N_ROWS / 128), 256, 0, stream>>>(z, cb, e_sq, tbk, tsd);
    merge_kernel<<<N_ROWS / 256, 256, 0, stream>>>(tbk, tsd, keys, flagcnt, flaglist);
    rescore_kernel<<<dim3(KCODES / 128, RCAP / 32), 256, 0, stream>>>(z, cb, e_sq, flagcnt, flaglist, keys);
    gather_stats_kernel<<<N_ROWS, 128, 0, stream>>>(z, cb, keys, out, cnt);
    finalize_kernel<<<(KCODES * DDIM + 255) / 256, 256, 0, stream>>>(cb, cnt, out);
}

// Round 3
// 1148.976 us; speedup vs baseline: 2.1491x; 1.8331x over previous
//
#include <hip/hip_runtime.h>
#include <hip/hip_bf16.h>

// Problem constants
#define N_ROWS 16384   // 8*2048
#define DDIM   512
#define KCODES 8192
#define BETA   0.25f
#define DECAY  0.99f
#define ONE_MINUS_DECAY 0.01f
#define EMA_EPS 1e-5f

// Output layout (floats, concatenated in reference return order)
#define O_Z    0                 // z_out: 8388608
#define O_LOSS 8388608           // vq_loss: 1
#define O_CS   8388609           // new_ema_cluster_size: 8192
#define O_AVG  8396801           // new_ema_embed_avg: 4194304
#define O_CB   12591105          // new_codebook: 4194304

// Workspace layout (bytes)
#define WS_CNT      0            // float[8192]
#define WS_ESQ      32768        // float[8192]
#define WS_FLAGCNT  65536        // int
#define WS_FLAGLIST 65792        // int[2048]
#define WS_KEYS     73984        // u64[16384]
#define WS_TBK      205056       // u64[16384*32] = 4 MB
#define WS_TSD      4399360      // f32[16384*32] = 2 MB

#define TAU  0.35f
#define RCAP 2048

typedef _Float16 half8  __attribute__((ext_vector_type(8)));
typedef float    floatx4 __attribute__((ext_vector_type(4)));

// monotone float->u32 (ascending), and inverse
__device__ __forceinline__ unsigned enc_f(float d) {
    unsigned ub = __float_as_uint(d);
    return (ub & 0x80000000u) ? ~ub : (ub | 0x80000000u);
}
__device__ __forceinline__ float dec_key(unsigned long long k) {
    unsigned ub = (unsigned)(k >> 32);
    ub = (ub & 0x80000000u) ? (ub ^ 0x80000000u) : ~ub;
    return __uint_as_float(ub);
}

// ---------------- Kernel A: e_sq[k] = sum(e[k]^2) ----------------
__global__ void esq_kernel(const float* __restrict__ cb, float* __restrict__ e_sq) {
    int k = blockIdx.x;
    int t = threadIdx.x; // 64 threads = 1 wave
    const float4* r = (const float4*)(cb + (size_t)k * DDIM);
    float4 a = r[t];
    float4 b = r[t + 64];
    float s = a.x*a.x + a.y*a.y + a.z*a.z + a.w*a.w
            + b.x*b.x + b.y*b.y + b.z*b.z + b.w*b.w;
    #pragma unroll
    for (int o = 32; o > 0; o >>= 1) s += __shfl_down(s, o);
    if (t == 0) e_sq[k] = s;
}

// ---------------- Kernel P: init EMA outputs + zero loss ----------------
__global__ void prepass_kernel(const float* __restrict__ ema_cs,
                               const float* __restrict__ ema_avg,
                               float* __restrict__ out) {
    int i = blockIdx.x * 256 + threadIdx.x;
    if (i < KCODES * DDIM) out[O_AVG + i] = DECAY * ema_avg[i];
    if (i < KCODES)        out[O_CS + i]  = DECAY * ema_cs[i];
    if (i == 0)            out[O_LOSS]    = 0.0f;
}

// ---------------- Kernel S: f16 MFMA screening ----------------
__global__ __launch_bounds__(256, 2) void screen_kernel(
    const float* __restrict__ z, const float* __restrict__ cb,
    const float* __restrict__ e_sq,
    unsigned long long* __restrict__ tbk, float* __restrict__ tsd) {
    __shared__ _Float16 zt[128 * 64];
    __shared__ _Float16 ct[256 * 64];
    __shared__ float eb_d1[2][128];
    __shared__ int   eb_c1[2][128];
    __shared__ float eb_d2[2][128];

    const int tid = threadIdx.x;
    const int bx = blockIdx.x;   // code tile (32)
    const int by = blockIdx.y;   // row tile (128)
    const int lane = tid & 63, wid = tid >> 6;
    const int wm = wid & 1, wn = wid >> 1;
    const int lr = lane & 15, lq = lane >> 4;

    floatx4 acc[4][8];
    #pragma unroll
    for (int i = 0; i < 4; i++)
        #pragma unroll
        for (int j = 0; j < 8; j++) acc[i][j] = floatx4{0.f, 0.f, 0.f, 0.f};

    for (int kc = 0; kc < DDIM; kc += 64) {
        #pragma unroll
        for (int l = 0; l < 8; l++) {
            int idx = tid + 256 * l;
            int row = idx >> 4, q = idx & 15;
            const float4 v = *(const float4*)&z[(size_t)(by * 128 + row) * DDIM + kc + q * 4];
            int a = row * 64 + (((q >> 1) ^ (row & 7)) << 3) + ((q & 1) << 2);
            auto p0 = __builtin_amdgcn_cvt_pkrtz(v.x, v.y);
            auto p1 = __builtin_amdgcn_cvt_pkrtz(v.z, v.w);
            float2 w; w.x = __builtin_bit_cast(float, p0); w.y = __builtin_bit_cast(float, p1);
            *(float2*)&zt[a] = w;
        }
        #pragma unroll
        for (int l = 0; l < 16; l++) {
            int idx = tid + 256 * l;
            int row = idx >> 4, q = idx & 15;
            const float4 v = *(const float4*)&cb[(size_t)(bx * 256 + row) * DDIM + kc + q * 4];
            int a = row * 64 + (((q >> 1) ^ (row & 7)) << 3) + ((q & 1) << 2);
            auto p0 = __builtin_amdgcn_cvt_pkrtz(v.x, v.y);
            auto p1 = __builtin_amdgcn_cvt_pkrtz(v.z, v.w);
            float2 w; w.x = __builtin_bit_cast(float, p0); w.y = __builtin_bit_cast(float, p1);
            *(float2*)&ct[a] = w;
        }
        __syncthreads();
        #pragma unroll
        for (int kk = 0; kk < 2; kk++) {
            half8 av[4];
            #pragma unroll
            for (int mt = 0; mt < 4; mt++) {
                int row = wm * 64 + mt * 16 + lr;
                av[mt] = *(const half8*)&zt[row * 64 + (((kk * 4 + lq) ^ (row & 7)) << 3)];
            }
            #pragma unroll
            for (int nt = 0; nt < 8; nt++) {
                int row = wn * 128 + nt * 16 + lr;
                half8 bv = *(const half8*)&ct[row * 64 + (((kk * 4 + lq) ^ (row & 7)) << 3)];
                #pragma unroll
                for (int mt = 0; mt < 4; mt++)
                    acc[mt][nt] = __builtin_amdgcn_mfma_f32_16x16x32_f16(av[mt], bv, acc[mt][nt], 0, 0, 0);
            }
        }
        __syncthreads();
    }

    float es[8];
    #pragma unroll
    for (int nt = 0; nt < 8; nt++) es[nt] = e_sq[bx * 256 + wn * 128 + nt * 16 + lr];

    #pragma unroll
    for (int mt = 0; mt < 4; mt++) {
        #pragma unroll
        for (int r = 0; r < 4; r++) {
            float d1 = 1e30f, d2 = 1e30f; int c1 = 0x7FFFFFFF;
            #pragma unroll
            for (int nt = 0; nt < 8; nt++) {
                float d = fmaf(-2.0f, acc[mt][nt][r], es[nt]);
                int c = bx * 256 + wn * 128 + nt * 16 + lr;
                bool better = (d < d1) || (d == d1 && c < c1);
                if (better) { d2 = d1; d1 = d; c1 = c; }
                else        { d2 = fminf(d2, d); }
            }
            #pragma unroll
            for (int off = 1; off < 16; off <<= 1) {
                float od1 = __shfl_xor(d1, off);
                int   oc1 = __shfl_xor(c1, off);
                float od2 = __shfl_xor(d2, off);
                bool better = (od1 < d1) || (od1 == d1 && oc1 < c1);
                if (better) { d2 = fminf(d1, od2); d1 = od1; c1 = oc1; }
                else        { d2 = fminf(d2, od1); }
            }
            if (lr == 0) {
                int row = wm * 64 + mt * 16 + lq * 4 + r;
                eb_d1[wn][row] = d1; eb_c1[wn][row] = c1; eb_d2[wn][row] = d2;
            }
        }
    }
    __syncthreads();
    if (tid < 128) {
        float d1a = eb_d1[0][tid], d2a = eb_d2[0][tid]; int c1a = eb_c1[0][tid];
        float d1b = eb_d1[1][tid], d2b = eb_d2[1][tid]; int c1b = eb_c1[1][tid];
        bool bbet = (d1b < d1a) || (d1b == d1a && c1b < c1a);
        float d1 = bbet ? d1b : d1a; int c1 = bbet ? c1b : c1a;
        float d2 = bbet ? fminf(d1a, d2b) : fminf(d2a, d1b);
        unsigned long long key = ((unsigned long long)enc_f(d1) << 32) | (unsigned)c1;
        int row_g = by * 128 + tid;
        tbk[(size_t)row_g * 32 + bx] = key;
        tsd[(size_t)row_g * 32 + bx] = d2;
    }
}

// ---------------- Kernel M: merge tiles, flag near-ties ----------------
__global__ void merge_kernel(const unsigned long long* __restrict__ tbk,
                             const float* __restrict__ tsd,
                             unsigned long long* __restrict__ keys,
                             int* __restrict__ flagcnt, int* __restrict__ flaglist) {
    int row = blockIdx.x * 256 + threadIdx.x;
    const unsigned long long* t = tbk + (size_t)row * 32;
    const float* s = tsd + (size_t)row * 32;
    unsigned long long kb = t[0];
    float sec = s[0];
    for (int i = 1; i < 32; i++) {
        unsigned long long k = t[i]; float s2 = s[i];
        if (k < kb) { sec = fminf(fminf(sec, s2), dec_key(kb)); kb = k; }
        else        { sec = fminf(sec, fminf(s2, dec_key(k))); }
    }
    float best = dec_key(kb);
    if (sec - best < TAU) {
        int pos = atomicAdd(flagcnt, 1);
        if (pos < RCAP) { flaglist[pos] = row; keys[row] = ~0ULL; }
        else keys[row] = kb;
    } else {
        keys[row] = kb;
    }
}

// ---------------- Kernel R: exact fp32 rescore of flagged rows ----------------
// Epilogue reduces in-block: ONE atomicMin per (row, block), not per thread.
__global__ __launch_bounds__(256) void rescore_kernel(
    const float* __restrict__ z, const float* __restrict__ cb,
    const float* __restrict__ e_sq, const int* __restrict__ flagcnt,
    const int* __restrict__ flaglist, unsigned long long* __restrict__ keys) {
    int n = *flagcnt; n = min(n, RCAP);
    int base = blockIdx.y * 32;
    if (base >= n) return;
    __shared__ float ech[128][65];
    __shared__ float zch[32][65];
    __shared__ int ridx[32];
    __shared__ unsigned long long redk[32][33];
    const int tid = threadIdx.x;
    const int bx = blockIdx.x;
    if (tid < 32) ridx[tid] = flaglist[min(base + tid, n - 1)];
    __syncthreads();
    const int tc = tid & 31, tg = tid >> 5;  // codes tc*4.., rows tg*4..
    float acc[4][4] = {};
    for (int kc = 0; kc < DDIM; kc += 64) {
        #pragma unroll
        for (int l = 0; l < 8; l++) {
            int idx = tid + 256 * l;
            int row = idx >> 4, q = idx & 15;
            float4 v = *(const float4*)&cb[(size_t)(bx * 128 + row) * DDIM + kc + q * 4];
            ech[row][q*4+0] = v.x; ech[row][q*4+1] = v.y; ech[row][q*4+2] = v.z; ech[row][q*4+3] = v.w;
        }
        #pragma unroll
        for (int l = 0; l < 2; l++) {
            int idx = tid + 256 * l;
            int row = idx >> 4, q = idx & 15;
            float4 v = *(const float4*)&z[(size_t)ridx[row] * DDIM + kc + q * 4];
            zch[row][q*4+0] = v.x; zch[row][q*4+1] = v.y; zch[row][q*4+2] = v.z; zch[row][q*4+3] = v.w;
        }
        __syncthreads();
        for (int k = 0; k < 64; k++) {
            float a0 = zch[tg*4+0][k], a1 = zch[tg*4+1][k], a2 = zch[tg*4+2][k], a3 = zch[tg*4+3][k];
            float b0 = ech[tc*4+0][k], b1 = ech[tc*4+1][k], b2 = ech[tc*4+2][k], b3 = ech[tc*4+3][k];
            acc[0][0] = fmaf(a0,b0,acc[0][0]); acc[0][1] = fmaf(a0,b1,acc[0][1]);
            acc[0][2] = fmaf(a0,b2,acc[0][2]); acc[0][3] = fmaf(a0,b3,acc[0][3]);
            acc[1][0] = fmaf(a1,b0,acc[1][0]); acc[1][1] = fmaf(a1,b1,acc[1][1]);
            acc[1][2] = fmaf(a1,b2,acc[1][2]); acc[1][3] = fmaf(a1,b3,acc[1][3]);
            acc[2][0] = fmaf(a2,b0,acc[2][0]); acc[2][1] = fmaf(a2,b1,acc[2][1]);
            acc[2][2] = fmaf(a2,b2,acc[2][2]); acc[2][3] = fmaf(a2,b3,acc[2][3]);
            acc[3][0] = fmaf(a3,b0,acc[3][0]); acc[3][1] = fmaf(a3,b1,acc[3][1]);
            acc[3][2] = fmaf(a3,b2,acc[3][2]); acc[3][3] = fmaf(a3,b3,acc[3][3]);
        }
        __syncthreads();
    }
    // per-thread best over its 4 codes, for each of its 4 rows
    #pragma unroll
    for (int i = 0; i < 4; i++) {
        unsigned long long bk = ~0ULL;
        #pragma unroll
        for (int j = 0; j < 4; j++) {
            int code = bx * 128 + tc * 4 + j;
            float d = fmaf(-2.0f, acc[i][j], e_sq[code]);
            unsigned long long key = ((unsigned long long)enc_f(d) << 32) | (unsigned)code;
            bk = (key < bk) ? key : bk;
        }
        redk[tg * 4 + i][tc] = bk;
    }
    __syncthreads();
    if (tid < 32) {
        unsigned long long b = redk[tid][0];
        #pragma unroll
        for (int t = 1; t < 32; t++) {
            unsigned long long v = redk[tid][t];
            b = (v < b) ? v : b;
        }
        atomicMin(&keys[ridx[tid]], b);
    }
}

// ---------------- Kernel C: gather z_q, loss, EMA scatter ----------------
__global__ __launch_bounds__(128) void gather_stats_kernel(
    const float* __restrict__ z, const float* __restrict__ cb,
    const unsigned long long* __restrict__ keys,
    float* __restrict__ out, float* __restrict__ cnt) {
    const int row = blockIdx.x;
    const int tid = threadIdx.x;
    const int idx = (int)(unsigned int)(keys[row] & 0xFFFFFFFFull);

    const float4 zv = ((const float4*)(z  + (size_t)row * DDIM))[tid];
    const float4 ev = ((const float4*)(cb + (size_t)idx * DDIM))[tid];
    ((float4*)(out + O_Z + (size_t)row * DDIM))[tid] = ev;

    float dx = zv.x - ev.x, dy = zv.y - ev.y, dz = zv.z - ev.z, dw = zv.w - ev.w;
    float s = dx*dx + dy*dy + dz*dz + dw*dw;

    float* o3 = out + O_AVG + (size_t)idx * DDIM + tid * 4;
    atomicAdd(o3 + 0, ONE_MINUS_DECAY * zv.x);
    atomicAdd(o3 + 1, ONE_MINUS_DECAY * zv.y);
    atomicAdd(o3 + 2, ONE_MINUS_DECAY * zv.z);
    atomicAdd(o3 + 3, ONE_MINUS_DECAY * zv.w);

    #pragma unroll
    for (int o = 32; o > 0; o >>= 1) s += __shfl_down(s, o);
    __shared__ float red[2];
    if ((tid & 63) == 0) red[tid >> 6] = s;
    __syncthreads();
    if (tid == 0) {
        atomicAdd(out + O_LOSS, (red[0] + red[1]) * (BETA / (float)DDIM));
        atomicAdd(&cnt[idx], 1.0f);
        atomicAdd(out + O_CS + idx, ONE_MINUS_DECAY);
    }
}

// ---------------- Kernel D: finalize codebook ----------------
__global__ void finalize_kernel(const float* __restrict__ cb,
                                const float* __restrict__ cnt,
                                float* __restrict__ out) {
    int i = blockIdx.x * 256 + threadIdx.x;
    if (i >= KCODES * DDIM) return;
    int k = i >> 9;
    float avg = out[O_AVG + i];
    float ncs = out[O_CS + k];
    float upd = avg / (ncs + EMA_EPS);
    out[O_CB + i] = (cnt[k] > 0.0f) ? upd : cb[i];
}

extern "C" void kernel_launch(void* const* d_in, const int* in_sizes, int n_in,
                              void* d_out, int out_size, void* d_ws, size_t ws_size,
                              hipStream_t stream) {
    const float* z       = (const float*)d_in[0];
    const float* cb      = (const float*)d_in[1];
    const float* ema_cs  = (const float*)d_in[2];
    const float* ema_avg = (const float*)d_in[3];
    float* out = (float*)d_out;

    float* cnt  = (float*)((char*)d_ws + WS_CNT);
    float* e_sq = (float*)((char*)d_ws + WS_ESQ);
    int* flagcnt = (int*)((char*)d_ws + WS_FLAGCNT);
    int* flaglist = (int*)((char*)d_ws + WS_FLAGLIST);
    unsigned long long* keys = (unsigned long long*)((char*)d_ws + WS_KEYS);
    unsigned long long* tbk = (unsigned long long*)((char*)d_ws + WS_TBK);
    float* tsd = (float*)((char*)d_ws + WS_TSD);

    hipMemsetAsync(cnt, 0, KCODES * sizeof(float), stream);
    hipMemsetAsync(flagcnt, 0, sizeof(int), stream);

    esq_kernel<<<KCODES, 64, 0, stream>>>(cb, e_sq);
    prepass_kernel<<<(KCODES * DDIM + 255) / 256, 256, 0, stream>>>(ema_cs, ema_avg, out);
    screen_kernel<<<dim3(KCODES / 256, N_ROWS / 128), 256, 0, stream>>>(z, cb, e_sq, tbk, tsd);
    merge_kernel<<<N_ROWS / 256, 256, 0, stream>>>(tbk, tsd, keys, flagcnt, flaglist);
    rescore_kernel<<<dim3(KCODES / 128, RCAP / 32), 256, 0, stream>>>(z, cb, e_sq, flagcnt, flaglist, keys);
    gather_stats_kernel<<<N_ROWS, 128, 0, stream>>>(z, cb, keys, out, cnt);
    finalize_kernel<<<(KCODES * DDIM + 255) / 256, 256, 0, stream>>>(cb, cnt, out);
}

// Round 4
// 731.235 us; speedup vs baseline: 3.3768x; 1.5713x over previous
//
#include <hip/hip_runtime.h>
#include <hip/hip_bf16.h>

// Problem constants
#define N_ROWS 16384   // 8*2048
#define DDIM   512
#define KCODES 8192
#define BETA   0.25f
#define DECAY  0.99f
#define ONE_MINUS_DECAY 0.01f
#define EMA_EPS 1e-5f

// Output layout (floats, concatenated in reference return order)
#define O_Z    0                 // z_out: 8388608
#define O_LOSS 8388608           // vq_loss: 1
#define O_CS   8388609           // new_ema_cluster_size: 8192
#define O_AVG  8396801           // new_ema_embed_avg: 4194304
#define O_CB   12591105          // new_codebook: 4194304

// Workspace layout (bytes)
#define WS_CNT      0            // float[8192]
#define WS_ESQ      32768        // float[8192]
#define WS_FLAGCNT  65536        // int
#define WS_FLAGLIST 65792        // int[2048]
#define WS_KEYS     73984        // u64[16384]
#define WS_TBK      205056       // u64[16384*32] = 4 MB
#define WS_TSD      4399360      // f32[16384*32] = 2 MB
#define WS_Z16      6496512      // f16[16384*512] = 16 MB
#define WS_CB16     23273728     // f16[8192*512] = 8 MB  (ends ~31.7 MB)

#define TAU  0.35f
#define RCAP 2048

typedef _Float16 half8  __attribute__((ext_vector_type(8)));
typedef float    floatx4 __attribute__((ext_vector_type(4)));

// monotone float->u32 (ascending), and inverse
__device__ __forceinline__ unsigned enc_f(float d) {
    unsigned ub = __float_as_uint(d);
    return (ub & 0x80000000u) ? ~ub : (ub | 0x80000000u);
}
__device__ __forceinline__ float dec_key(unsigned long long k) {
    unsigned ub = (unsigned)(k >> 32);
    ub = (ub & 0x80000000u) ? (ub ^ 0x80000000u) : ~ub;
    return __uint_as_float(ub);
}

__device__ __forceinline__ float4 pack8_f16(float4 a, float4 b) {
    auto p0 = __builtin_amdgcn_cvt_pkrtz(a.x, a.y);
    auto p1 = __builtin_amdgcn_cvt_pkrtz(a.z, a.w);
    auto p2 = __builtin_amdgcn_cvt_pkrtz(b.x, b.y);
    auto p3 = __builtin_amdgcn_cvt_pkrtz(b.z, b.w);
    float4 r;
    r.x = __builtin_bit_cast(float, p0);
    r.y = __builtin_bit_cast(float, p1);
    r.z = __builtin_bit_cast(float, p2);
    r.w = __builtin_bit_cast(float, p3);
    return r;
}

// global->LDS direct DMA, 16 B per lane. LDS dest = wave-uniform base + lane*16.
__device__ __forceinline__ void load_lds16(const void* g, void* l) {
    __builtin_amdgcn_global_load_lds(
        (const __attribute__((address_space(1))) unsigned int*)g,
        (__attribute__((address_space(3))) unsigned int*)l, 16, 0, 0);
}

// ---------------- Kernel Z: z fp32 -> f16 ----------------
__global__ __launch_bounds__(256) void cvtz_kernel(const float* __restrict__ z,
                                                   _Float16* __restrict__ z16) {
    size_t i = (size_t)blockIdx.x * 256 + threadIdx.x;   // 8 elems per thread
    const float4* p = (const float4*)z + 2 * i;
    ((float4*)z16)[i] = pack8_f16(p[0], p[1]);
}

// ---------------- Kernel B: cb fp32 -> f16  +  e_sq ----------------
__global__ __launch_bounds__(64) void cvtcb_kernel(const float* __restrict__ cb,
                                                   _Float16* __restrict__ cb16,
                                                   float* __restrict__ e_sq) {
    int k = blockIdx.x;
    int t = threadIdx.x; // 64 threads, 8 elems each
    const float4* r = (const float4*)(cb + (size_t)k * DDIM);
    float4 a = r[2 * t], b = r[2 * t + 1];
    ((float4*)(cb16 + (size_t)k * DDIM))[t] = pack8_f16(a, b);
    float s = a.x*a.x + a.y*a.y + a.z*a.z + a.w*a.w
            + b.x*b.x + b.y*b.y + b.z*b.z + b.w*b.w;
    #pragma unroll
    for (int o = 32; o > 0; o >>= 1) s += __shfl_down(s, o);
    if (t == 0) e_sq[k] = s;
}

// ---------------- Kernel P: init EMA outputs + zero loss ----------------
__global__ void prepass_kernel(const float* __restrict__ ema_cs,
                               const float* __restrict__ ema_avg,
                               float* __restrict__ out) {
    int i = blockIdx.x * 256 + threadIdx.x;
    if (i < KCODES * DDIM) out[O_AVG + i] = DECAY * ema_avg[i];
    if (i < KCODES)        out[O_CS + i]  = DECAY * ema_cs[i];
    if (i == 0)            out[O_LOSS]    = 0.0f;
}

// ---------------- Kernel S: f16 MFMA screening ----------------
// 256 thr (4 waves), tile 128 rows x 256 codes, BK=64. global_load_lds staging:
// LDS granule g=(round*4+wave)*64+lane at bytes g*16; global source address
// carries the XOR swizzle (physical kq holds logical kq^(row&7)) so the
// ds_read_b128 fragment reads stay conflict-free (R3: SQ_LDS_BANK_CONFLICT=0).
__global__ __launch_bounds__(256, 2) void screen_kernel(
    const _Float16* __restrict__ z16, const _Float16* __restrict__ cb16,
    const float* __restrict__ e_sq,
    unsigned long long* __restrict__ tbk, float* __restrict__ tsd) {
    __shared__ _Float16 zt[128 * 64];   // 16 KB
    __shared__ _Float16 ct[256 * 64];   // 32 KB
    __shared__ float eb_d1[2][128];
    __shared__ int   eb_c1[2][128];
    __shared__ float eb_d2[2][128];

    const int tid = threadIdx.x;
    const int bx = blockIdx.x;   // code tile (32)
    const int by = blockIdx.y;   // row tile (128)
    const int lane = tid & 63, wid = tid >> 6;
    const int wm = wid & 1, wn = wid >> 1;
    const int lr = lane & 15, lq = lane >> 4;

    // staging source pointers (per-lane, loop-invariant) + LDS dests (wave-uniform)
    const _Float16* zsrc[4]; _Float16* zdst[4];
    #pragma unroll
    for (int r = 0; r < 4; r++) {
        int g = (r * 4 + wid) * 64 + lane;
        int row = g >> 3, kq = g & 7;
        zsrc[r] = z16 + (size_t)(by * 128 + row) * DDIM + ((kq ^ (row & 7)) << 3);
        zdst[r] = &zt[(r * 4 + wid) * 512];
    }
    const _Float16* csrc[8]; _Float16* cdst[8];
    #pragma unroll
    for (int r = 0; r < 8; r++) {
        int g = (r * 4 + wid) * 64 + lane;
        int row = g >> 3, kq = g & 7;
        csrc[r] = cb16 + (size_t)(bx * 256 + row) * DDIM + ((kq ^ (row & 7)) << 3);
        cdst[r] = &ct[(r * 4 + wid) * 512];
    }

    floatx4 acc[4][8];
    #pragma unroll
    for (int i = 0; i < 4; i++)
        #pragma unroll
        for (int j = 0; j < 8; j++) acc[i][j] = floatx4{0.f, 0.f, 0.f, 0.f};

    for (int kc = 0; kc < DDIM; kc += 64) {
        #pragma unroll
        for (int r = 0; r < 4; r++) load_lds16(zsrc[r] + kc, zdst[r]);
        #pragma unroll
        for (int r = 0; r < 8; r++) load_lds16(csrc[r] + kc, cdst[r]);
        __syncthreads();   // drains vmcnt (loads landed) before reads
        #pragma unroll
        for (int kk = 0; kk < 2; kk++) {
            half8 av[4];
            #pragma unroll
            for (int mt = 0; mt < 4; mt++) {
                int row = wm * 64 + mt * 16 + lr;
                av[mt] = *(const half8*)&zt[row * 64 + (((kk * 4 + lq) ^ (row & 7)) << 3)];
            }
            #pragma unroll
            for (int nt = 0; nt < 8; nt++) {
                int row = wn * 128 + nt * 16 + lr;
                half8 bv = *(const half8*)&ct[row * 64 + (((kk * 4 + lq) ^ (row & 7)) << 3)];
                #pragma unroll
                for (int mt = 0; mt < 4; mt++)
                    acc[mt][nt] = __builtin_amdgcn_mfma_f32_16x16x32_f16(av[mt], bv, acc[mt][nt], 0, 0, 0);
            }
        }
        __syncthreads();   // all ds_reads done before next overwrite
    }

    float es[8];
    #pragma unroll
    for (int nt = 0; nt < 8; nt++) es[nt] = e_sq[bx * 256 + wn * 128 + nt * 16 + lr];

    #pragma unroll
    for (int mt = 0; mt < 4; mt++) {
        #pragma unroll
        for (int r = 0; r < 4; r++) {
            float d1 = 1e30f, d2 = 1e30f; int c1 = 0x7FFFFFFF;
            #pragma unroll
            for (int nt = 0; nt < 8; nt++) {
                float d = fmaf(-2.0f, acc[mt][nt][r], es[nt]);
                int c = bx * 256 + wn * 128 + nt * 16 + lr;
                bool better = (d < d1) || (d == d1 && c < c1);
                if (better) { d2 = d1; d1 = d; c1 = c; }
                else        { d2 = fminf(d2, d); }
            }
            #pragma unroll
            for (int off = 1; off < 16; off <<= 1) {
                float od1 = __shfl_xor(d1, off);
                int   oc1 = __shfl_xor(c1, off);
                float od2 = __shfl_xor(d2, off);
                bool better = (od1 < d1) || (od1 == d1 && oc1 < c1);
                if (better) { d2 = fminf(d1, od2); d1 = od1; c1 = oc1; }
                else        { d2 = fminf(d2, od1); }
            }
            if (lr == 0) {
                int row = wm * 64 + mt * 16 + lq * 4 + r;
                eb_d1[wn][row] = d1; eb_c1[wn][row] = c1; eb_d2[wn][row] = d2;
            }
        }
    }
    __syncthreads();
    if (tid < 128) {
        float d1a = eb_d1[0][tid], d2a = eb_d2[0][tid]; int c1a = eb_c1[0][tid];
        float d1b = eb_d1[1][tid], d2b = eb_d2[1][tid]; int c1b = eb_c1[1][tid];
        bool bbet = (d1b < d1a) || (d1b == d1a && c1b < c1a);
        float d1 = bbet ? d1b : d1a; int c1 = bbet ? c1b : c1a;
        float d2 = bbet ? fminf(d1a, d2b) : fminf(d2a, d1b);
        unsigned long long key = ((unsigned long long)enc_f(d1) << 32) | (unsigned)c1;
        int row_g = by * 128 + tid;
        tbk[(size_t)row_g * 32 + bx] = key;
        tsd[(size_t)row_g * 32 + bx] = d2;
    }
}

// ---------------- Kernel M: merge tiles, flag near-ties ----------------
__global__ void merge_kernel(const unsigned long long* __restrict__ tbk,
                             const float* __restrict__ tsd,
                             unsigned long long* __restrict__ keys,
                             int* __restrict__ flagcnt, int* __restrict__ flaglist) {
    int row = blockIdx.x * 256 + threadIdx.x;
    const unsigned long long* t = tbk + (size_t)row * 32;
    const float* s = tsd + (size_t)row * 32;
    unsigned long long kb = t[0];
    float sec = s[0];
    for (int i = 1; i < 32; i++) {
        unsigned long long k = t[i]; float s2 = s[i];
        if (k < kb) { sec = fminf(fminf(sec, s2), dec_key(kb)); kb = k; }
        else        { sec = fminf(sec, fminf(s2, dec_key(k))); }
    }
    float best = dec_key(kb);
    if (sec - best < TAU) {
        int pos = atomicAdd(flagcnt, 1);
        if (pos < RCAP) { flaglist[pos] = row; keys[row] = ~0ULL; }
        else keys[row] = kb;
    } else {
        keys[row] = kb;
    }
}

// ---------------- Kernel R: exact fp32 rescore of flagged rows ----------------
__global__ __launch_bounds__(256) void rescore_kernel(
    const float* __restrict__ z, const float* __restrict__ cb,
    const float* __restrict__ e_sq, const int* __restrict__ flagcnt,
    const int* __restrict__ flaglist, unsigned long long* __restrict__ keys) {
    int n = *flagcnt; n = min(n, RCAP);
    int base = blockIdx.y * 32;
    if (base >= n) return;
    __shared__ float ech[128][65];
    __shared__ float zch[32][65];
    __shared__ int ridx[32];
    __shared__ unsigned long long redk[32][33];
    const int tid = threadIdx.x;
    const int bx = blockIdx.x;
    if (tid < 32) ridx[tid] = flaglist[min(base + tid, n - 1)];
    __syncthreads();
    const int tc = tid & 31, tg = tid >> 5;
    float acc[4][4] = {};
    for (int kc = 0; kc < DDIM; kc += 64) {
        #pragma unroll
        for (int l = 0; l < 8; l++) {
            int idx = tid + 256 * l;
            int row = idx >> 4, q = idx & 15;
            float4 v = *(const float4*)&cb[(size_t)(bx * 128 + row) * DDIM + kc + q * 4];
            ech[row][q*4+0] = v.x; ech[row][q*4+1] = v.y; ech[row][q*4+2] = v.z; ech[row][q*4+3] = v.w;
        }
        #pragma unroll
        for (int l = 0; l < 2; l++) {
            int idx = tid + 256 * l;
            int row = idx >> 4, q = idx & 15;
            float4 v = *(const float4*)&z[(size_t)ridx[row] * DDIM + kc + q * 4];
            zch[row][q*4+0] = v.x; zch[row][q*4+1] = v.y; zch[row][q*4+2] = v.z; zch[row][q*4+3] = v.w;
        }
        __syncthreads();
        for (int k = 0; k < 64; k++) {
            float a0 = zch[tg*4+0][k], a1 = zch[tg*4+1][k], a2 = zch[tg*4+2][k], a3 = zch[tg*4+3][k];
            float b0 = ech[tc*4+0][k], b1 = ech[tc*4+1][k], b2 = ech[tc*4+2][k], b3 = ech[tc*4+3][k];
            acc[0][0] = fmaf(a0,b0,acc[0][0]); acc[0][1] = fmaf(a0,b1,acc[0][1]);
            acc[0][2] = fmaf(a0,b2,acc[0][2]); acc[0][3] = fmaf(a0,b3,acc[0][3]);
            acc[1][0] = fmaf(a1,b0,acc[1][0]); acc[1][1] = fmaf(a1,b1,acc[1][1]);
            acc[1][2] = fmaf(a1,b2,acc[1][2]); acc[1][3] = fmaf(a1,b3,acc[1][3]);
            acc[2][0] = fmaf(a2,b0,acc[2][0]); acc[2][1] = fmaf(a2,b1,acc[2][1]);
            acc[2][2] = fmaf(a2,b2,acc[2][2]); acc[2][3] = fmaf(a2,b3,acc[2][3]);
            acc[3][0] = fmaf(a3,b0,acc[3][0]); acc[3][1] = fmaf(a3,b1,acc[3][1]);
            acc[3][2] = fmaf(a3,b2,acc[3][2]); acc[3][3] = fmaf(a3,b3,acc[3][3]);
        }
        __syncthreads();
    }
    #pragma unroll
    for (int i = 0; i < 4; i++) {
        unsigned long long bk = ~0ULL;
        #pragma unroll
        for (int j = 0; j < 4; j++) {
            int code = bx * 128 + tc * 4 + j;
            float d = fmaf(-2.0f, acc[i][j], e_sq[code]);
            unsigned long long key = ((unsigned long long)enc_f(d) << 32) | (unsigned)code;
            bk = (key < bk) ? key : bk;
        }
        redk[tg * 4 + i][tc] = bk;
    }
    __syncthreads();
    if (tid < 32) {
        unsigned long long b = redk[tid][0];
        #pragma unroll
        for (int t = 1; t < 32; t++) {
            unsigned long long v = redk[tid][t];
            b = (v < b) ? v : b;
        }
        atomicMin(&keys[ridx[tid]], b);
    }
}

// ---------------- Kernel C: gather z_q, loss, EMA scatter ----------------
__global__ __launch_bounds__(128) void gather_stats_kernel(
    const float* __restrict__ z, const float* __restrict__ cb,
    const unsigned long long* __restrict__ keys,
    float* __restrict__ out, float* __restrict__ cnt) {
    const int row = blockIdx.x;
    const int tid = threadIdx.x;
    const int idx = (int)(unsigned int)(keys[row] & 0xFFFFFFFFull);

    const float4 zv = ((const float4*)(z  + (size_t)row * DDIM))[tid];
    const float4 ev = ((const float4*)(cb + (size_t)idx * DDIM))[tid];
    ((float4*)(out + O_Z + (size_t)row * DDIM))[tid] = ev;

    float dx = zv.x - ev.x, dy = zv.y - ev.y, dz = zv.z - ev.z, dw = zv.w - ev.w;
    float s = dx*dx + dy*dy + dz*dz + dw*dw;

    float* o3 = out + O_AVG + (size_t)idx * DDIM + tid * 4;
    atomicAdd(o3 + 0, ONE_MINUS_DECAY * zv.x);
    atomicAdd(o3 + 1, ONE_MINUS_DECAY * zv.y);
    atomicAdd(o3 + 2, ONE_MINUS_DECAY * zv.z);
    atomicAdd(o3 + 3, ONE_MINUS_DECAY * zv.w);

    #pragma unroll
    for (int o = 32; o > 0; o >>= 1) s += __shfl_down(s, o);
    __shared__ float red[2];
    if ((tid & 63) == 0) red[tid >> 6] = s;
    __syncthreads();
    if (tid == 0) {
        atomicAdd(out + O_LOSS, (red[0] + red[1]) * (BETA / (float)DDIM));
        atomicAdd(&cnt[idx], 1.0f);
        atomicAdd(out + O_CS + idx, ONE_MINUS_DECAY);
    }
}

// ---------------- Kernel D: finalize codebook ----------------
__global__ void finalize_kernel(const float* __restrict__ cb,
                                const float* __restrict__ cnt,
                                float* __restrict__ out) {
    int i = blockIdx.x * 256 + threadIdx.x;
    if (i >= KCODES * DDIM) return;
    int k = i >> 9;
    float avg = out[O_AVG + i];
    float ncs = out[O_CS + k];
    float upd = avg / (ncs + EMA_EPS);
    out[O_CB + i] = (cnt[k] > 0.0f) ? upd : cb[i];
}

extern "C" void kernel_launch(void* const* d_in, const int* in_sizes, int n_in,
                              void* d_out, int out_size, void* d_ws, size_t ws_size,
                              hipStream_t stream) {
    const float* z       = (const float*)d_in[0];
    const float* cb      = (const float*)d_in[1];
    const float* ema_cs  = (const float*)d_in[2];
    const float* ema_avg = (const float*)d_in[3];
    float* out = (float*)d_out;

    float* cnt  = (float*)((char*)d_ws + WS_CNT);
    float* e_sq = (float*)((char*)d_ws + WS_ESQ);
    int* flagcnt = (int*)((char*)d_ws + WS_FLAGCNT);
    int* flaglist = (int*)((char*)d_ws + WS_FLAGLIST);
    unsigned long long* keys = (unsigned long long*)((char*)d_ws + WS_KEYS);
    unsigned long long* tbk = (unsigned long long*)((char*)d_ws + WS_TBK);
    float* tsd = (float*)((char*)d_ws + WS_TSD);
    _Float16* z16  = (_Float16*)((char*)d_ws + WS_Z16);
    _Float16* cb16 = (_Float16*)((char*)d_ws + WS_CB16);

    hipMemsetAsync(cnt, 0, KCODES * sizeof(float), stream);
    hipMemsetAsync(flagcnt, 0, sizeof(int), stream);

    cvtz_kernel<<<N_ROWS * DDIM / 8 / 256, 256, 0, stream>>>(z, z16);
    cvtcb_kernel<<<KCODES, 64, 0, stream>>>(cb, cb16, e_sq);
    prepass_kernel<<<(KCODES * DDIM + 255) / 256, 256, 0, stream>>>(ema_cs, ema_avg, out);
    screen_kernel<<<dim3(KCODES / 256, N_ROWS / 128), 256, 0, stream>>>(z16, cb16, e_sq, tbk, tsd);
    merge_kernel<<<N_ROWS / 256, 256, 0, stream>>>(tbk, tsd, keys, flagcnt, flaglist);
    rescore_kernel<<<dim3(KCODES / 128, RCAP / 32), 256, 0, stream>>>(z, cb, e_sq, flagcnt, flaglist, keys);
    gather_stats_kernel<<<N_ROWS, 128, 0, stream>>>(z, cb, keys, out, cnt);
    finalize_kernel<<<(KCODES * DDIM + 255) / 256, 256, 0, stream>>>(cb, cnt, out);
}

// Round 5
// 646.773 us; speedup vs baseline: 3.8178x; 1.1306x over previous
//
#include <hip/hip_runtime.h>
#include <hip/hip_bf16.h>

// Problem constants
#define N_ROWS 16384   // 8*2048
#define DDIM   512
#define KCODES 8192
#define BETA   0.25f
#define DECAY  0.99f
#define ONE_MINUS_DECAY 0.01f
#define EMA_EPS 1e-5f

// Output layout (floats, concatenated in reference return order)
#define O_Z    0                 // z_out: 8388608
#define O_LOSS 8388608           // vq_loss: 1
#define O_CS   8388609           // new_ema_cluster_size: 8192
#define O_AVG  8396801           // new_ema_embed_avg: 4194304
#define O_CB   12591105          // new_codebook: 4194304

// Workspace layout (bytes), all 256-aligned; total ~25.5 MB
#define WS_CNT      0            // int[8192]            32 KB
#define WS_ESQ      32768        // float[8192]          32 KB
#define WS_FLAGCNT  65536        // int (+pad)           256 B
#define WS_FLAGLIST 65792        // int[2048]            8 KB
#define WS_KEYS     73984        // u64[16384]           128 KB
#define WS_SEC2     205056       // u32[16384]           64 KB
#define WS_LOSSP    270592       // float[64]            256 B
#define WS_IDXS     270848       // int[16384]           64 KB
#define WS_OFFS     336384       // int[8192]            32 KB
#define WS_CURS     369152       // int[8192]            32 KB
#define WS_ROWLIST  401920       // int[16384]           64 KB
#define WS_Z16      467456       // f16[16384*512]       16 MB
#define WS_CB16     17244672     // f16[8192*512]        8 MB   (end ~25.6 MB)

#define TAU  0.35f
#define RCAP 2048

typedef _Float16 half8  __attribute__((ext_vector_type(8)));
typedef float    floatx4 __attribute__((ext_vector_type(4)));

// monotone float<->u32 (ascending order preserved)
__device__ __forceinline__ unsigned enc_f(float d) {
    unsigned ub = __float_as_uint(d);
    return (ub & 0x80000000u) ? ~ub : (ub | 0x80000000u);
}
__device__ __forceinline__ float dec32(unsigned ub) {
    return __uint_as_float((ub & 0x80000000u) ? (ub ^ 0x80000000u) : ~ub);
}
__device__ __forceinline__ float dec_key(unsigned long long k) {
    return dec32((unsigned)(k >> 32));
}

__device__ __forceinline__ float4 pack8_f16(float4 a, float4 b) {
    auto p0 = __builtin_amdgcn_cvt_pkrtz(a.x, a.y);
    auto p1 = __builtin_amdgcn_cvt_pkrtz(a.z, a.w);
    auto p2 = __builtin_amdgcn_cvt_pkrtz(b.x, b.y);
    auto p3 = __builtin_amdgcn_cvt_pkrtz(b.z, b.w);
    float4 r;
    r.x = __builtin_bit_cast(float, p0);
    r.y = __builtin_bit_cast(float, p1);
    r.z = __builtin_bit_cast(float, p2);
    r.w = __builtin_bit_cast(float, p3);
    return r;
}

// global->LDS direct DMA, 16 B per lane. LDS dest = wave-uniform base + lane*16.
__device__ __forceinline__ void load_lds16(const void* g, void* l) {
    __builtin_amdgcn_global_load_lds(
        (const __attribute__((address_space(1))) unsigned int*)g,
        (__attribute__((address_space(3))) unsigned int*)l, 16, 0, 0);
}

// ---------------- cvtz: z fp32 -> f16 ----------------
__global__ __launch_bounds__(256) void cvtz_kernel(const float* __restrict__ z,
                                                   _Float16* __restrict__ z16) {
    size_t i = (size_t)blockIdx.x * 256 + threadIdx.x;   // 8 elems per thread
    const float4* p = (const float4*)z + 2 * i;
    ((float4*)z16)[i] = pack8_f16(p[0], p[1]);
}

// ---------------- cvtcb: cb fp32 -> f16 + e_sq ----------------
__global__ __launch_bounds__(64) void cvtcb_kernel(const float* __restrict__ cb,
                                                   _Float16* __restrict__ cb16,
                                                   float* __restrict__ e_sq) {
    int k = blockIdx.x;
    int t = threadIdx.x;
    const float4* r = (const float4*)(cb + (size_t)k * DDIM);
    float4 a = r[2 * t], b = r[2 * t + 1];
    ((float4*)(cb16 + (size_t)k * DDIM))[t] = pack8_f16(a, b);
    float s = a.x*a.x + a.y*a.y + a.z*a.z + a.w*a.w
            + b.x*b.x + b.y*b.y + b.z*b.z + b.w*b.w;
    #pragma unroll
    for (int o = 32; o > 0; o >>= 1) s += __shfl_down(s, o);
    if (t == 0) e_sq[k] = s;
}

// ---------------- screen: f16 MFMA, 128x128 tile ----------------
// 256 thr (4 waves, 2x2), wave tile 64x64, acc[4][4] -> 64 acc regs.
// LDS 32 KB; epilogue arrays aliased into zt. Best/second via atomicMin.
__global__ __launch_bounds__(256, 4) void screen_kernel(
    const _Float16* __restrict__ z16, const _Float16* __restrict__ cb16,
    const float* __restrict__ e_sq,
    unsigned long long* __restrict__ keys, unsigned* __restrict__ sec2) {
    __shared__ _Float16 zt[128 * 64];   // 16 KB (reused for epilogue)
    __shared__ _Float16 ct[128 * 64];   // 16 KB

    const int tid = threadIdx.x;
    const int by = blockIdx.x;   // row tile (128)
    const int bx = blockIdx.y;   // code tile (64)
    const int lane = tid & 63, wid = tid >> 6;
    const int wm = wid & 1, wn = wid >> 1;
    const int lr = lane & 15, lq = lane >> 4;

    // staging pointers: granule g = (r*4+wid)*64+lane; row=g>>3, kq=g&7;
    // source carries XOR swizzle so ds_read_b128 frags stay conflict-free.
    const _Float16* zsrc[4]; const _Float16* csrc[4];
    #pragma unroll
    for (int r = 0; r < 4; r++) {
        int g = (r * 4 + wid) * 64 + lane;
        int row = g >> 3, kq = g & 7;
        zsrc[r] = z16 + (size_t)(by * 128 + row) * DDIM + ((kq ^ (row & 7)) << 3);
        csrc[r] = cb16 + (size_t)(bx * 128 + row) * DDIM + ((kq ^ (row & 7)) << 3);
    }

    floatx4 acc[4][4];
    #pragma unroll
    for (int i = 0; i < 4; i++)
        #pragma unroll
        for (int j = 0; j < 4; j++) acc[i][j] = floatx4{0.f, 0.f, 0.f, 0.f};

    for (int kc = 0; kc < DDIM; kc += 64) {
        #pragma unroll
        for (int r = 0; r < 4; r++) load_lds16(zsrc[r] + kc, &zt[(r * 4 + wid) * 512]);
        #pragma unroll
        for (int r = 0; r < 4; r++) load_lds16(csrc[r] + kc, &ct[(r * 4 + wid) * 512]);
        __syncthreads();
        #pragma unroll
        for (int kk = 0; kk < 2; kk++) {
            half8 av[4];
            #pragma unroll
            for (int mt = 0; mt < 4; mt++) {
                int row = wm * 64 + mt * 16 + lr;
                av[mt] = *(const half8*)&zt[row * 64 + (((kk * 4 + lq) ^ (row & 7)) << 3)];
            }
            #pragma unroll
            for (int nt = 0; nt < 4; nt++) {
                int row = wn * 64 + nt * 16 + lr;
                half8 bv = *(const half8*)&ct[row * 64 + (((kk * 4 + lq) ^ (row & 7)) << 3)];
                #pragma unroll
                for (int mt = 0; mt < 4; mt++)
                    acc[mt][nt] = __builtin_amdgcn_mfma_f32_16x16x32_f16(av[mt], bv, acc[mt][nt], 0, 0, 0);
            }
        }
        __syncthreads();
    }

    // epilogue scratch aliased onto zt (all ds_reads drained by loop-end barrier)
    float* eb_d1 = (float*)zt;            // [2][128]
    int*   eb_c1 = (int*)zt + 256;        // [2][128]
    float* eb_d2 = (float*)zt + 512;      // [2][128]

    float es[4];
    #pragma unroll
    for (int nt = 0; nt < 4; nt++) es[nt] = e_sq[bx * 128 + wn * 64 + nt * 16 + lr];

    #pragma unroll
    for (int mt = 0; mt < 4; mt++) {
        #pragma unroll
        for (int r = 0; r < 4; r++) {
            float d1 = 1e30f, d2 = 1e30f; int c1 = 0x7FFFFFFF;
            #pragma unroll
            for (int nt = 0; nt < 4; nt++) {
                float d = fmaf(-2.0f, acc[mt][nt][r], es[nt]);
                int c = bx * 128 + wn * 64 + nt * 16 + lr;
                bool better = (d < d1) || (d == d1 && c < c1);
                if (better) { d2 = d1; d1 = d; c1 = c; }
                else        { d2 = fminf(d2, d); }
            }
            #pragma unroll
            for (int off = 1; off < 16; off <<= 1) {
                float od1 = __shfl_xor(d1, off);
                int   oc1 = __shfl_xor(c1, off);
                float od2 = __shfl_xor(d2, off);
                bool better = (od1 < d1) || (od1 == d1 && oc1 < c1);
                if (better) { d2 = fminf(d1, od2); d1 = od1; c1 = oc1; }
                else        { d2 = fminf(d2, od1); }
            }
            if (lr == 0) {
                int row = wm * 64 + mt * 16 + lq * 4 + r;
                eb_d1[wn * 128 + row] = d1; eb_c1[wn * 128 + row] = c1; eb_d2[wn * 128 + row] = d2;
            }
        }
    }
    __syncthreads();
    if (tid < 128) {
        float d1a = eb_d1[tid],       d2a = eb_d2[tid];       int c1a = eb_c1[tid];
        float d1b = eb_d1[128 + tid], d2b = eb_d2[128 + tid]; int c1b = eb_c1[128 + tid];
        bool bbet = (d1b < d1a) || (d1b == d1a && c1b < c1a);
        float d1 = bbet ? d1b : d1a; int c1 = bbet ? c1b : c1a;
        float d2 = bbet ? fminf(d1a, d2b) : fminf(d2a, d1b);
        unsigned long long key = ((unsigned long long)enc_f(d1) << 32) | (unsigned)c1;
        int row_g = by * 128 + tid;
        unsigned long long old = atomicMin(&keys[row_g], key);
        // second-best candidate: if we displaced old best, old's dist is a cand;
        // else our d1 is a cand. d2 always a cand. (fminf(NaN,x)=x handles init.)
        float cand = (key < old) ? fminf(dec_key(old), d2) : fminf(d1, d2);
        atomicMin(&sec2[row_g], enc_f(cand));
    }
}

// ---------------- merge: flag near-ties ----------------
__global__ void merge_kernel(unsigned long long* __restrict__ keys,
                             const unsigned* __restrict__ sec2,
                             int* __restrict__ flagcnt, int* __restrict__ flaglist) {
    int row = blockIdx.x * 256 + threadIdx.x;
    unsigned long long kb = keys[row];
    float best = dec_key(kb);
    float sec  = dec32(sec2[row]);
    if (sec - best < TAU) {
        int pos = atomicAdd(flagcnt, 1);
        if (pos < RCAP) { flaglist[pos] = row; keys[row] = ~0ULL; }
    }
}

// ---------------- rescore: exact fp32 over flagged rows ----------------
__global__ __launch_bounds__(256) void rescore_kernel(
    const float* __restrict__ z, const float* __restrict__ cb,
    const float* __restrict__ e_sq, const int* __restrict__ flagcnt,
    const int* __restrict__ flaglist, unsigned long long* __restrict__ keys) {
    int n = *flagcnt; n = min(n, RCAP);
    int base = blockIdx.y * 32;
    if (base >= n) return;
    __shared__ float ech[128][65];
    __shared__ float zch[32][65];
    __shared__ int ridx[32];
    __shared__ unsigned long long redk[32][33];
    const int tid = threadIdx.x;
    const int bx = blockIdx.x;
    if (tid < 32) ridx[tid] = flaglist[min(base + tid, n - 1)];
    __syncthreads();
    const int tc = tid & 31, tg = tid >> 5;
    float acc[4][4] = {};
    for (int kc = 0; kc < DDIM; kc += 64) {
        #pragma unroll
        for (int l = 0; l < 8; l++) {
            int idx = tid + 256 * l;
            int row = idx >> 4, q = idx & 15;
            float4 v = *(const float4*)&cb[(size_t)(bx * 128 + row) * DDIM + kc + q * 4];
            ech[row][q*4+0] = v.x; ech[row][q*4+1] = v.y; ech[row][q*4+2] = v.z; ech[row][q*4+3] = v.w;
        }
        #pragma unroll
        for (int l = 0; l < 2; l++) {
            int idx = tid + 256 * l;
            int row = idx >> 4, q = idx & 15;
            float4 v = *(const float4*)&z[(size_t)ridx[row] * DDIM + kc + q * 4];
            zch[row][q*4+0] = v.x; zch[row][q*4+1] = v.y; zch[row][q*4+2] = v.z; zch[row][q*4+3] = v.w;
        }
        __syncthreads();
        for (int k = 0; k < 64; k++) {
            float a0 = zch[tg*4+0][k], a1 = zch[tg*4+1][k], a2 = zch[tg*4+2][k], a3 = zch[tg*4+3][k];
            float b0 = ech[tc*4+0][k], b1 = ech[tc*4+1][k], b2 = ech[tc*4+2][k], b3 = ech[tc*4+3][k];
            acc[0][0] = fmaf(a0,b0,acc[0][0]); acc[0][1] = fmaf(a0,b1,acc[0][1]);
            acc[0][2] = fmaf(a0,b2,acc[0][2]); acc[0][3] = fmaf(a0,b3,acc[0][3]);
            acc[1][0] = fmaf(a1,b0,acc[1][0]); acc[1][1] = fmaf(a1,b1,acc[1][1]);
            acc[1][2] = fmaf(a1,b2,acc[1][2]); acc[1][3] = fmaf(a1,b3,acc[1][3]);
            acc[2][0] = fmaf(a2,b0,acc[2][0]); acc[2][1] = fmaf(a2,b1,acc[2][1]);
            acc[2][2] = fmaf(a2,b2,acc[2][2]); acc[2][3] = fmaf(a2,b3,acc[2][3]);
            acc[3][0] = fmaf(a3,b0,acc[3][0]); acc[3][1] = fmaf(a3,b1,acc[3][1]);
            acc[3][2] = fmaf(a3,b2,acc[3][2]); acc[3][3] = fmaf(a3,b3,acc[3][3]);
        }
        __syncthreads();
    }
    #pragma unroll
    for (int i = 0; i < 4; i++) {
        unsigned long long bk = ~0ULL;
        #pragma unroll
        for (int j = 0; j < 4; j++) {
            int code = bx * 128 + tc * 4 + j;
            float d = fmaf(-2.0f, acc[i][j], e_sq[code]);
            unsigned long long key = ((unsigned long long)enc_f(d) << 32) | (unsigned)code;
            bk = (key < bk) ? key : bk;
        }
        redk[tg * 4 + i][tc] = bk;
    }
    __syncthreads();
    if (tid < 32) {
        unsigned long long b = redk[tid][0];
        #pragma unroll
        for (int t = 1; t < 32; t++) {
            unsigned long long v = redk[tid][t];
            b = (v < b) ? v : b;
        }
        atomicMin(&keys[ridx[tid]], b);
    }
}

// ---------------- C0: z_out, loss partials, counts, idx list ----------------
__global__ __launch_bounds__(128) void zout_loss_kernel(
    const float* __restrict__ z, const float* __restrict__ cb,
    const unsigned long long* __restrict__ keys,
    float* __restrict__ out, int* __restrict__ cnt,
    int* __restrict__ idxs, float* __restrict__ lossp) {
    const int row = blockIdx.x;
    const int tid = threadIdx.x;
    const int idx = (int)(unsigned int)(keys[row] & 0xFFFFFFFFull);

    const float4 zv = ((const float4*)(z  + (size_t)row * DDIM))[tid];
    const float4 ev = ((const float4*)(cb + (size_t)idx * DDIM))[tid];
    ((float4*)(out + O_Z + (size_t)row * DDIM))[tid] = ev;

    float dx = zv.x - ev.x, dy = zv.y - ev.y, dz = zv.z - ev.z, dw = zv.w - ev.w;
    float s = dx*dx + dy*dy + dz*dz + dw*dw;

    #pragma unroll
    for (int o = 32; o > 0; o >>= 1) s += __shfl_down(s, o);
    __shared__ float red[2];
    if ((tid & 63) == 0) red[tid >> 6] = s;
    __syncthreads();
    if (tid == 0) {
        atomicAdd(&lossp[row & 63], red[0] + red[1]);
        atomicAdd(&cnt[idx], 1);
        idxs[row] = idx;
    }
}

// ---------------- loss finalize ----------------
__global__ void loss_final_kernel(const float* __restrict__ lossp, float* __restrict__ out) {
    float s = lossp[threadIdx.x];
    #pragma unroll
    for (int o = 32; o > 0; o >>= 1) s += __shfl_down(s, o);
    if (threadIdx.x == 0) out[O_LOSS] = s * (BETA / (float)DDIM);
}

// ---------------- C2: scan counts -> offsets; new_ema_cluster_size ----------------
__global__ __launch_bounds__(256) void scan_kernel(
    const int* __restrict__ cnt, const float* __restrict__ ema_cs,
    float* __restrict__ out, int* __restrict__ offs, int* __restrict__ curs) {
    __shared__ int tot[256];
    const int t = threadIdx.x;
    const int base = t * 32;
    int local[32]; int s = 0;
    #pragma unroll
    for (int j = 0; j < 32; j++) { local[j] = cnt[base + j]; s += local[j]; }
    tot[t] = s;
    __syncthreads();
    for (int off = 1; off < 256; off <<= 1) {
        int v = (t >= off) ? tot[t - off] : 0;
        __syncthreads();
        tot[t] += v;
        __syncthreads();
    }
    int run = tot[t] - s;  // exclusive prefix
    #pragma unroll
    for (int j = 0; j < 32; j++) {
        offs[base + j] = run; curs[base + j] = run;
        out[O_CS + base + j] = DECAY * ema_cs[base + j] + ONE_MINUS_DECAY * (float)local[j];
        run += local[j];
    }
}

// ---------------- C3: fill rowlist ----------------
__global__ void fill_kernel(const int* __restrict__ idxs, int* __restrict__ curs,
                            int* __restrict__ rowlist) {
    int row = blockIdx.x * 256 + threadIdx.x;
    int idx = idxs[row];
    int pos = atomicAdd(&curs[idx], 1);
    rowlist[pos] = row;
}

// ---------------- C4: per-code EMA avg + codebook update ----------------
// 1 wave per code: gather its rows from z, fold decay + divide + active mask.
__global__ __launch_bounds__(256) void code_update_kernel(
    const float* __restrict__ z, const float* __restrict__ cb,
    const float* __restrict__ ema_cs, const float* __restrict__ ema_avg,
    const int* __restrict__ cnt, const int* __restrict__ offs,
    const int* __restrict__ rowlist, float* __restrict__ out) {
    const int lane = threadIdx.x & 63;
    const int k = blockIdx.x * 4 + (threadIdx.x >> 6);
    const int n = cnt[k], off = offs[k];
    float4 a0 = {0.f,0.f,0.f,0.f}, a1 = {0.f,0.f,0.f,0.f};
    for (int r = 0; r < n; r++) {
        int row = rowlist[off + r];
        const float4* zp = (const float4*)(z + (size_t)row * DDIM) + lane * 2;
        float4 v0 = zp[0], v1 = zp[1];
        a0.x += v0.x; a0.y += v0.y; a0.z += v0.z; a0.w += v0.w;
        a1.x += v1.x; a1.y += v1.y; a1.z += v1.z; a1.w += v1.w;
    }
    const float4* ep = (const float4*)(ema_avg + (size_t)k * DDIM) + lane * 2;
    float4 e0 = ep[0], e1 = ep[1];
    float4 n0, n1;
    n0.x = DECAY * e0.x + ONE_MINUS_DECAY * a0.x; n0.y = DECAY * e0.y + ONE_MINUS_DECAY * a0.y;
    n0.z = DECAY * e0.z + ONE_MINUS_DECAY * a0.z; n0.w = DECAY * e0.w + ONE_MINUS_DECAY * a0.w;
    n1.x = DECAY * e1.x + ONE_MINUS_DECAY * a1.x; n1.y = DECAY * e1.y + ONE_MINUS_DECAY * a1.y;
    n1.z = DECAY * e1.z + ONE_MINUS_DECAY * a1.z; n1.w = DECAY * e1.w + ONE_MINUS_DECAY * a1.w;
    ((float4*)(out + O_AVG + (size_t)k * DDIM))[lane * 2]     = n0;
    ((float4*)(out + O_AVG + (size_t)k * DDIM))[lane * 2 + 1] = n1;

    float ncs = DECAY * ema_cs[k] + ONE_MINUS_DECAY * (float)n;
    float inv = 1.0f / (ncs + EMA_EPS);
    float4 c0, c1;
    if (n > 0) {
        c0.x = n0.x * inv; c0.y = n0.y * inv; c0.z = n0.z * inv; c0.w = n0.w * inv;
        c1.x = n1.x * inv; c1.y = n1.y * inv; c1.z = n1.z * inv; c1.w = n1.w * inv;
    } else {
        const float4* cp = (const float4*)(cb + (size_t)k * DDIM) + lane * 2;
        c0 = cp[0]; c1 = cp[1];
    }
    ((float4*)(out + O_CB + (size_t)k * DDIM))[lane * 2]     = c0;
    ((float4*)(out + O_CB + (size_t)k * DDIM))[lane * 2 + 1] = c1;
}

extern "C" void kernel_launch(void* const* d_in, const int* in_sizes, int n_in,
                              void* d_out, int out_size, void* d_ws, size_t ws_size,
                              hipStream_t stream) {
    const float* z       = (const float*)d_in[0];
    const float* cb      = (const float*)d_in[1];
    const float* ema_cs  = (const float*)d_in[2];
    const float* ema_avg = (const float*)d_in[3];
    float* out = (float*)d_out;

    int* cnt       = (int*)((char*)d_ws + WS_CNT);
    float* e_sq    = (float*)((char*)d_ws + WS_ESQ);
    int* flagcnt   = (int*)((char*)d_ws + WS_FLAGCNT);
    int* flaglist  = (int*)((char*)d_ws + WS_FLAGLIST);
    unsigned long long* keys = (unsigned long long*)((char*)d_ws + WS_KEYS);
    unsigned* sec2 = (unsigned*)((char*)d_ws + WS_SEC2);
    float* lossp   = (float*)((char*)d_ws + WS_LOSSP);
    int* idxs      = (int*)((char*)d_ws + WS_IDXS);
    int* offs      = (int*)((char*)d_ws + WS_OFFS);
    int* curs      = (int*)((char*)d_ws + WS_CURS);
    int* rowlist   = (int*)((char*)d_ws + WS_ROWLIST);
    _Float16* z16  = (_Float16*)((char*)d_ws + WS_Z16);
    _Float16* cb16 = (_Float16*)((char*)d_ws + WS_CB16);

    hipMemsetAsync(cnt, 0, KCODES * sizeof(int), stream);
    hipMemsetAsync(flagcnt, 0, sizeof(int), stream);
    hipMemsetAsync(keys, 0xFF, N_ROWS * sizeof(unsigned long long), stream);
    hipMemsetAsync(sec2, 0xFF, N_ROWS * sizeof(unsigned), stream);
    hipMemsetAsync(lossp, 0, 64 * sizeof(float), stream);

    cvtz_kernel<<<N_ROWS * DDIM / 8 / 256, 256, 0, stream>>>(z, z16);
    cvtcb_kernel<<<KCODES, 64, 0, stream>>>(cb, cb16, e_sq);
    screen_kernel<<<dim3(N_ROWS / 128, KCODES / 128), 256, 0, stream>>>(z16, cb16, e_sq, keys, sec2);
    merge_kernel<<<N_ROWS / 256, 256, 0, stream>>>(keys, sec2, flagcnt, flaglist);
    rescore_kernel<<<dim3(KCODES / 128, RCAP / 32), 256, 0, stream>>>(z, cb, e_sq, flagcnt, flaglist, keys);
    zout_loss_kernel<<<N_ROWS, 128, 0, stream>>>(z, cb, keys, out, cnt, idxs, lossp);
    loss_final_kernel<<<1, 64, 0, stream>>>(lossp, out);
    scan_kernel<<<1, 256, 0, stream>>>(cnt, ema_cs, out, offs, curs);
    fill_kernel<<<N_ROWS / 256, 256, 0, stream>>>(idxs, curs, rowlist);
    code_update_kernel<<<KCODES / 4, 256, 0, stream>>>(z, cb, ema_cs, ema_avg, cnt, offs, rowlist, out);
}